// Round 14
// baseline (177.712 us; speedup 1.0000x reference)
//
#include <hip/hip_runtime.h>

#define P 7
#define NCH 256
#define NPP 49
#define LDS_CAP 1280   // provable max Hr*stride ≈ 1186 (see region-bound proof)

__global__ __launch_bounds__(256) void pooler_kernel(
    const float* __restrict__ boxes,
    const int* __restrict__ batch_ids,
    const float* __restrict__ g0, const float* __restrict__ g1,
    const float* __restrict__ g2, const float* __restrict__ g3,
    float* __restrict__ out)
{
    __shared__ float sreg[4][LDS_CAP];   // 20 KB -> 8 blocks/CU

    const int n    = blockIdx.y;          // box
    const int cg   = blockIdx.x;          // channel group 0..63
    const int lane = threadIdx.x;         // 0..63
    const int wy   = threadIdx.y;         // wave = channel within group
    const int c    = (cg << 2) | wy;

    // ---- box + level (uniform within block) ----
    const float x1i = boxes[n*4+0], y1i = boxes[n*4+1];
    const float x2i = boxes[n*4+2], y2i = boxes[n*4+3];
    const float area = (x2i - x1i) * (y2i - y1i);
    float lvlf = floorf(4.0f + log2f(sqrtf(area) / 224.0f + 1e-6f));
    lvlf = fminf(fmaxf(lvlf, 2.0f), 5.0f);
    const int lvl = (int)lvlf - 2;        // 0..3

    const float* feat = (lvl==0) ? g0 : (lvl==1) ? g1 : (lvl==2) ? g2 : g3;
    const int    L    = (lvl==0) ? 200 : (lvl==1) ? 100 : (lvl==2) ? 50 : 25;
    const float scale = (lvl==0) ? 0.25f : (lvl==1) ? 0.125f
                      : (lvl==2) ? 0.0625f : 0.03125f;
    const int b = batch_ids[n];

    const float x1 = x1i * scale, y1 = y1i * scale;
    const float bw = fmaxf(x2i*scale - x1, 1.0f) * (1.0f/7.0f);
    const float bh = fmaxf(y2i*scale - y1, 1.0f) * (1.0f/7.0f);
    const float Lf = (float)L, Lm1 = Lf - 1.0f;
    const int   Lm2 = L - 2;

    // ---- region bounds (monotone prep over samples g in [0.25, 6.75]) ----
    const int rx0 = min((int)fminf(fmaxf(x1 + 0.25f*bw, 0.0f), Lm1), Lm2);
    const int rx1 = min((int)fminf(fmaxf(x1 + 6.75f*bw, 0.0f), Lm1), Lm2);
    const int ry0 = min((int)fminf(fmaxf(y1 + 0.25f*bh, 0.0f), Lm1), Lm2);
    const int ry1 = min((int)fminf(fmaxf(y1 + 6.75f*bh, 0.0f), Lm1), Lm2);
    const int Wr = rx1 - rx0 + 2;         // region cols incl. +1 tap column
    const int Hr = ry1 - ry0 + 2;         // region rows incl. +1 tap row
    const int stride = Wr | 1;            // odd row stride -> bank-spread

    // ---- stage region -> LDS: row-wise, lane = col (coalesced, ~3 VALU/elt)
    {
        const float* gp = feat + ((size_t)b * NCH + c) * (size_t)(L * L)
                        + (size_t)ry0 * L + rx0;
        float* sp = sreg[wy];
        for (int r = 0; r < Hr; ++r) {
            for (int c0 = lane; c0 < Wr; c0 += 64)   // 1 iter for Wr<=64
                sp[c0] = gp[c0];
            gp += L;
            sp += stride;
        }
    }
    __syncthreads();

    // ---- bilinear interpolation from LDS (lanes 0..48 = bins) ----
    if (lane < NPP) {
        const int py = lane / P;
        const int px = lane - py * P;

        int   y0[2], x0[2];
        float fy[2], hy[2], vy[2], fx[2], hx[2], vx[2];
#pragma unroll
        for (int s = 0; s < 2; ++s) {
            const float yc = y1 + ((float)py + (s ? 0.75f : 0.25f)) * bh;
            vy[s] = (yc > -1.0f && yc < Lf) ? 1.0f : 0.0f;
            const float ycc = fminf(fmaxf(yc, 0.0f), Lm1);
            y0[s] = min((int)ycc, Lm2);
            fy[s] = ycc - (float)y0[s];
            hy[s] = 1.0f - fy[s];

            const float xc = x1 + ((float)px + (s ? 0.75f : 0.25f)) * bw;
            vx[s] = (xc > -1.0f && xc < Lf) ? 1.0f : 0.0f;
            const float xcc = fminf(fmaxf(xc, 0.0f), Lm1);
            x0[s] = min((int)xcc, Lm2);
            fx[s] = xcc - (float)x0[s];
            hx[s] = 1.0f - fx[s];
        }

        const float* s0 = sreg[wy];
        float acc = 0.0f;
#pragma unroll
        for (int sy = 0; sy < 2; ++sy) {
            const int rowa = (y0[sy] - ry0) * stride - rx0;
#pragma unroll
            for (int sx = 0; sx < 2; ++sx) {
                const int a = rowa + x0[sx];
                const float v00 = s0[a];
                const float v01 = s0[a + 1];
                const float v10 = s0[a + stride];
                const float v11 = s0[a + stride + 1];
                acc += (vy[sy] * vx[sx])
                     * (hy[sy] * (hx[sx] * v00 + fx[sx] * v01)
                      + fy[sy] * (hx[sx] * v10 + fx[sx] * v11));
            }
        }
        out[((size_t)n * NCH + c) * NPP + lane] = acc * 0.25f;
    }
}

extern "C" void kernel_launch(void* const* d_in, const int* in_sizes, int n_in,
                              void* d_out, int out_size, void* d_ws, size_t ws_size,
                              hipStream_t stream) {
    const float* boxes     = (const float*)d_in[0];
    const int*   batch_ids = (const int*)d_in[1];
    const float* g0        = (const float*)d_in[2];
    const float* g1        = (const float*)d_in[3];
    const float* g2        = (const float*)d_in[4];
    const float* g3        = (const float*)d_in[5];
    float* out = (float*)d_out;

    const int N = in_sizes[0] / 4;                 // 512
    dim3 block(64, 4);                             // 4 waves = 4 channels
    dim3 grid(NCH / 4, N);                         // (64, 512)
    pooler_kernel<<<grid, block, 0, stream>>>(boxes, batch_ids, g0, g1, g2, g3, out);
}

// Round 15
// 71.135 us; speedup vs baseline: 2.4982x; 2.4982x over previous
//
#include <hip/hip_runtime.h>

#define P 7
#define NCH 256
#define NPP 49
#define LDS_CAP 1280   // provable max Hr*stride <= ~1186 (region-bound proof r9)

__global__ __launch_bounds__(256) void pooler_kernel(
    const float* __restrict__ boxes,
    const int* __restrict__ batch_ids,
    const float* __restrict__ g0, const float* __restrict__ g1,
    const float* __restrict__ g2, const float* __restrict__ g3,
    float* __restrict__ out)
{
    __shared__ float sreg[4][LDS_CAP];   // 20 KB; sreg[wy] is WAVE-PRIVATE

    const int n    = blockIdx.y;          // box
    const int cg   = blockIdx.x;          // channel group 0..63
    const int lane = threadIdx.x;         // 0..63
    const int wy   = threadIdx.y;         // wave index = channel within group
    const int c    = (cg << 2) | wy;

    // ---- box + level (uniform within block) ----
    const float x1i = boxes[n*4+0], y1i = boxes[n*4+1];
    const float x2i = boxes[n*4+2], y2i = boxes[n*4+3];
    const float area = (x2i - x1i) * (y2i - y1i);
    float lvlf = floorf(4.0f + log2f(sqrtf(area) / 224.0f + 1e-6f));
    lvlf = fminf(fmaxf(lvlf, 2.0f), 5.0f);
    const int lvl = (int)lvlf - 2;        // 0..3

    const float* feat = (lvl==0) ? g0 : (lvl==1) ? g1 : (lvl==2) ? g2 : g3;
    const int    L    = (lvl==0) ? 200 : (lvl==1) ? 100 : (lvl==2) ? 50 : 25;
    const float scale = (lvl==0) ? 0.25f : (lvl==1) ? 0.125f
                      : (lvl==2) ? 0.0625f : 0.03125f;
    const int b = batch_ids[n];

    const float x1 = x1i * scale, y1 = y1i * scale;
    const float bw = fmaxf(x2i*scale - x1, 1.0f) * (1.0f/7.0f);
    const float bh = fmaxf(y2i*scale - y1, 1.0f) * (1.0f/7.0f);
    const float Lf = (float)L, Lm1 = Lf - 1.0f;
    const int   Lm2 = L - 2;

    // ---- region bounds (monotone prep over samples g in [0.25, 6.75]) ----
    const int rx0 = min((int)fminf(fmaxf(x1 + 0.25f*bw, 0.0f), Lm1), Lm2);
    const int rx1 = min((int)fminf(fmaxf(x1 + 6.75f*bw, 0.0f), Lm1), Lm2);
    const int ry0 = min((int)fminf(fmaxf(y1 + 0.25f*bh, 0.0f), Lm1), Lm2);
    const int ry1 = min((int)fminf(fmaxf(y1 + 6.75f*bh, 0.0f), Lm1), Lm2);
    const int Wr = rx1 - rx0 + 2;
    const int Hr = ry1 - ry0 + 2;
    const int stride = Wr | 1;            // odd row stride -> bank-spread
    const int T  = Wr * Hr;               // uniform across the block
    const float rcpW = 1.0f / (float)Wr;

    const float* gp = feat + ((size_t)b * NCH + c) * (size_t)(L * L);
    const int gbase = ry0 * L + rx0;
    float* sp = sreg[wy];

    // ---- stage region -> LDS: flat index, 4 clamped loads in flight ----
    // element f: row=floor(f/Wr) via float-rcp (+0.5 margin), col=f-row*Wr
#define STAGE4(FBASE)                                                        \
    {                                                                        \
        int   fA[4]; int aA[4]; float vA[4]; int gA[4];                      \
        _Pragma("unroll")                                                    \
        for (int k = 0; k < 4; ++k) {                                        \
            const int f  = (FBASE) + (k << 6);                               \
            const int fc = min(f, T - 1);            /* clamp: always valid */\
            const int row = (int)(((float)fc + 0.5f) * rcpW);                \
            const int col = fc - row * Wr;                                   \
            fA[k] = f;                                                       \
            gA[k] = gbase + row * L + col;                                   \
            aA[k] = row * stride + col;                                      \
        }                                                                    \
        _Pragma("unroll")                                                    \
        for (int k = 0; k < 4; ++k) vA[k] = gp[gA[k]];   /* 4 independent */ \
        _Pragma("unroll")                                                    \
        for (int k = 0; k < 4; ++k) if (fA[k] < T) sp[aA[k]] = vA[k];        \
    }

    if (T <= 256) {
        STAGE4(lane);                      // one pass, no loop (most blocks)
    } else {
        for (int f0 = lane; f0 < T; f0 += 256)
            STAGE4(f0);
    }
    // NO __syncthreads(): sreg[wy] is written and read only by wave wy;
    // compiler-inserted vmcnt/lgkmcnt orders load->ds_write->ds_read.

    // ---- bilinear interpolation from LDS (lanes 0..48 = bins) ----
    if (lane < NPP) {
        const int py = lane / P;
        const int px = lane - py * P;

        int   y0[2], x0[2];
        float fy[2], hy[2], vy[2], fx[2], hx[2], vx[2];
#pragma unroll
        for (int s = 0; s < 2; ++s) {
            const float yc = y1 + ((float)py + (s ? 0.75f : 0.25f)) * bh;
            vy[s] = (yc > -1.0f && yc < Lf) ? 1.0f : 0.0f;
            const float ycc = fminf(fmaxf(yc, 0.0f), Lm1);
            y0[s] = min((int)ycc, Lm2);
            fy[s] = ycc - (float)y0[s];
            hy[s] = 1.0f - fy[s];

            const float xc = x1 + ((float)px + (s ? 0.75f : 0.25f)) * bw;
            vx[s] = (xc > -1.0f && xc < Lf) ? 1.0f : 0.0f;
            const float xcc = fminf(fmaxf(xc, 0.0f), Lm1);
            x0[s] = min((int)xcc, Lm2);
            fx[s] = xcc - (float)x0[s];
            hx[s] = 1.0f - fx[s];
        }

        float acc = 0.0f;
#pragma unroll
        for (int sy = 0; sy < 2; ++sy) {
            const int rowa = (y0[sy] - ry0) * stride - rx0;
#pragma unroll
            for (int sx = 0; sx < 2; ++sx) {
                const int a = rowa + x0[sx];
                const float v00 = sp[a];
                const float v01 = sp[a + 1];
                const float v10 = sp[a + stride];
                const float v11 = sp[a + stride + 1];
                acc += (vy[sy] * vx[sx])
                     * (hy[sy] * (hx[sx] * v00 + fx[sx] * v01)
                      + fy[sy] * (hx[sx] * v10 + fx[sx] * v11));
            }
        }
        out[((size_t)n * NCH + c) * NPP + lane] = acc * 0.25f;
    }
}

extern "C" void kernel_launch(void* const* d_in, const int* in_sizes, int n_in,
                              void* d_out, int out_size, void* d_ws, size_t ws_size,
                              hipStream_t stream) {
    const float* boxes     = (const float*)d_in[0];
    const int*   batch_ids = (const int*)d_in[1];
    const float* g0        = (const float*)d_in[2];
    const float* g1        = (const float*)d_in[3];
    const float* g2        = (const float*)d_in[4];
    const float* g3        = (const float*)d_in[5];
    float* out = (float*)d_out;

    const int N = in_sizes[0] / 4;                 // 512
    dim3 block(64, 4);                             // 4 waves = 4 channels
    dim3 grid(NCH / 4, N);                         // (64, 512)
    pooler_kernel<<<grid, block, 0, stream>>>(boxes, batch_ids, g0, g1, g2, g3, out);
}